// Round 8
// baseline (144.845 us; speedup 1.0000x reference)
//
#include <hip/hip_runtime.h>
#include <hip/hip_bf16.h>

// Reference collapses: softmax over singleton axis==1 -> attention weights == 1,
// so ctx[b,h] = sum_l fmap[b,l,h], out[b,t,c] = dot(ctx[b,:], W_gen[c,:]) + b_gen[c]
// broadcast over all t. LSTM / embedding / text are dead code.
//
// R8 = INSTRUMENTATION round: R5's kernels (best, 24.5us) wrapped in reps=12
// idempotent loops so each dispatch becomes long enough to surface in the
// rocprof top-5 with per-kernel counters. dur_R8 ≈ 12*(K1+K2) + OV and
// dur_R5 = K1+K2+OV solve the kernel/overhead split.

constexpr int Hd = 512;   // hidden (K)
constexpr int Cd = 4096;  // classes (N)
constexpr int Bd = 64;    // batch (M)
constexpr int Td = 32;    // timesteps (broadcast)
constexpr int Ld = 256;   // FH*FW
constexpr int CG = 32;    // c per block in K2
constexpr int REPS = 12;

// all-DPP 16-lane rotate-add; 0x121:ror1 0x122:ror2 0x124:ror4 0x128:ror8
template<int CTRL>
__device__ __forceinline__ float ror_add(float v) {
    int r = __builtin_amdgcn_update_dpp(0, __float_as_int(v), CTRL, 0xF, 0xF, false);
    return v + __int_as_float(r);
}

// ---------------- K1: ctx[row] = sum of 256 contiguous floats (x reps) ----------
__global__ __launch_bounds__(256) void reduce_rows(const float* in,
                                                   float* ctx, int reps) {
    const int lane = threadIdx.x & 63;
    const int gw   = blockIdx.x * 4 + (threadIdx.x >> 6);
    const int row0 = gw * 8;
    const float4* in4 = reinterpret_cast<const float4*>(in);

    for (int it = 0; it < reps; ++it) {
        float4 v[8];
        #pragma unroll
        for (int r = 0; r < 8; ++r)
            v[r] = in4[(size_t)(row0 + r) * 64 + lane];
        float s[8];
        #pragma unroll
        for (int r = 0; r < 8; ++r) {
            float a = v[r].x + v[r].y + v[r].z + v[r].w;
            a += __shfl_xor(a, 16, 64);
            a += __shfl_xor(a, 32, 64);
            a = ror_add<0x121>(a);
            a = ror_add<0x122>(a);
            a = ror_add<0x124>(a);
            a = ror_add<0x128>(a);
            s[r] = a;
        }
        if (lane < 8) {
            float val = s[0];
            #pragma unroll
            for (int r = 1; r < 8; ++r) val = (lane == r) ? s[r] : val;
            ctx[row0 + lane] = val;
        }
        asm volatile("" ::: "memory");   // force re-execution each rep
    }
}

// ---------------- K2: out = ctx·W^T + bias, bcast over t (x reps) ---------------
__global__ __launch_bounds__(256) void gemm_bcast(const float* ctx,
                                                  const float* Wgen,
                                                  const float* bgen,
                                                  float* out, int reps) {
    __shared__ float part[4 * CG * 4];  // [wave][c_local][b_local]
    const int tid   = threadIdx.x;
    const int w     = tid >> 6;
    const int lane  = tid & 63;
    const int cpart = lane >> 4;
    const int hp    = lane & 15;
    const int cblk  = blockIdx.x * CG;
    const int b0    = blockIdx.y * 4;

    const float4* W4 = reinterpret_cast<const float4*>(Wgen);
    const float4* X4 = reinterpret_cast<const float4*>(ctx);

    for (int it = 0; it < reps; ++it) {
        float4 xr[4][2];
        #pragma unroll
        for (int bb = 0; bb < 4; ++bb)
            #pragma unroll
            for (int j = 0; j < 2; ++j)
                xr[bb][j] = X4[(size_t)(b0 + bb) * 128 + w * 32 + j * 16 + hp];

        #pragma unroll
        for (int q = 0; q < CG / 4; ++q) {
            const int c = cblk + q * 4 + cpart;
            const size_t base = (size_t)c * 128 + w * 32 + hp;
            const float4 w0 = W4[base];
            const float4 w1 = W4[base + 16];
            float acc[4];
            #pragma unroll
            for (int bb = 0; bb < 4; ++bb) {
                float a = w0.x * xr[bb][0].x + w0.y * xr[bb][0].y
                        + w0.z * xr[bb][0].z + w0.w * xr[bb][0].w
                        + w1.x * xr[bb][1].x + w1.y * xr[bb][1].y
                        + w1.z * xr[bb][1].z + w1.w * xr[bb][1].w;
                a = ror_add<0x128>(a);
                a = ror_add<0x124>(a);
                a = ror_add<0x122>(a);
                a = ror_add<0x121>(a);
                acc[bb] = a;
            }
            if (hp == 0) {
                reinterpret_cast<float4*>(part)[w * CG + (q * 4 + cpart)] =
                    make_float4(acc[0], acc[1], acc[2], acc[3]);
            }
        }
        __syncthreads();

        {
            const int cq = tid & 7;
            const int bl = (tid >> 3) & 3;
            const int tt = tid >> 5;
            float v[4];
            #pragma unroll
            for (int j = 0; j < 4; ++j) {
                const int cl = cq * 4 + j;
                v[j] = part[(0 * CG + cl) * 4 + bl] + part[(1 * CG + cl) * 4 + bl]
                     + part[(2 * CG + cl) * 4 + bl] + part[(3 * CG + cl) * 4 + bl]
                     + bgen[cblk + cl];
            }
            const float4 vv = make_float4(v[0], v[1], v[2], v[3]);
            float* o = out + (size_t)(b0 + bl) * Td * Cd + cblk + cq * 4;
            #pragma unroll
            for (int k = 0; k < 4; ++k) {
                const int t = tt + k * 8;
                *reinterpret_cast<float4*>(o + (size_t)t * Cd) = vv;
            }
        }
        __syncthreads();                 // part/final reuse across reps
        asm volatile("" ::: "memory");   // force re-execution each rep
    }
}

extern "C" void kernel_launch(void* const* d_in, const int* in_sizes, int n_in,
                              void* d_out, int out_size, void* d_ws, size_t ws_size,
                              hipStream_t stream) {
    const float* fmap = (const float*)d_in[0];   // [64,512,8,32]
    const float* Wgen = (const float*)d_in[9];   // [4096,512]
    const float* bgen = (const float*)d_in[10];  // [4096]
    float* out = (float*)d_out;                  // [64,32,4096]
    float* ctx = (float*)d_ws;                   // [64,512] scratch

    reduce_rows<<<dim3((Bd * Hd) / (4 * 8)), dim3(256), 0, stream>>>(fmap, ctx, REPS);
    gemm_bcast<<<dim3(Cd / CG, Bd / 4), dim3(256), 0, stream>>>(ctx, Wgen, bgen, out, REPS);
}

// Round 9
// 27.484 us; speedup vs baseline: 5.2701x; 5.2701x over previous
//
#include <hip/hip_runtime.h>
#include <hip/hip_bf16.h>

// Reference collapses: softmax over singleton axis==1 -> attention weights == 1,
// so ctx[b,h] = sum_l fmap[b,l,h], out[b,t,c] = dot(ctx[b,:], W_gen[c,:]) + b_gen[c]
// broadcast over all t. LSTM / embedding / text are dead code.
//
// R8 instrumentation: K1+K2 ~= 10.9us, fixed overhead ~= 13.6us, K2 ~9.5us of
// which ~5.3 is the compulsory 33.5MB write. R9 = R5 + (a) LDS pad 4->5 to kill
// the 768K/invocation 8-way bank conflicts in the combine read, (b) packed
// v_pk_fma_f32 for the dot product (halves scalar FMA count).

constexpr int Hd = 512;   // hidden (K)
constexpr int Cd = 4096;  // classes (N)
constexpr int Bd = 64;    // batch (M)
constexpr int Td = 32;    // timesteps (broadcast)
constexpr int Ld = 256;   // FH*FW
constexpr int CG = 32;    // c per block in K2
constexpr int PS = 5;     // padded stride for part[] (floats per (wave,c) entry)

typedef float f2 __attribute__((ext_vector_type(2)));

__device__ __forceinline__ void pkfma(f2& acc, f2 a, f2 b) {
    asm("v_pk_fma_f32 %0, %1, %2, %0" : "+v"(acc) : "v"(a), "v"(b));
}

// all-DPP 16-lane rotate-add; 0x121:ror1 0x122:ror2 0x124:ror4 0x128:ror8
template<int CTRL>
__device__ __forceinline__ float ror_add(float v) {
    int r = __builtin_amdgcn_update_dpp(0, __float_as_int(v), CTRL, 0xF, 0xF, false);
    return v + __int_as_float(r);
}

// ---------------- K1: ctx[row] = sum of 256 contiguous floats ----------------
// grid 1024 x 256thr; wave = 8 rows, loads all issued up front. (unchanged R5)
__global__ __launch_bounds__(256) void reduce_rows(const float* __restrict__ in,
                                                   float* __restrict__ ctx) {
    const int lane = threadIdx.x & 63;
    const int gw   = blockIdx.x * 4 + (threadIdx.x >> 6);
    const int row0 = gw * 8;
    const float4* in4 = reinterpret_cast<const float4*>(in);

    float4 v[8];
    #pragma unroll
    for (int r = 0; r < 8; ++r)
        v[r] = in4[(size_t)(row0 + r) * 64 + lane];

    float s[8];
    #pragma unroll
    for (int r = 0; r < 8; ++r) {
        float a = v[r].x + v[r].y + v[r].z + v[r].w;
        a += __shfl_xor(a, 16, 64);
        a += __shfl_xor(a, 32, 64);
        a = ror_add<0x121>(a);
        a = ror_add<0x122>(a);
        a = ror_add<0x124>(a);
        a = ror_add<0x128>(a);
        s[r] = a;
    }
    if (lane < 8) {
        float val = s[0];
        #pragma unroll
        for (int r = 1; r < 8; ++r) val = (lane == r) ? s[r] : val;
        ctx[row0 + lane] = val;
    }
}

// ---------------- K2: out[b][t][c] = ctx[b,:]·W[c,:] + bias, bcast over t -------
// grid (128, 16) = 2048 blocks (R5's winning geometry), 4 waves.
__global__ __launch_bounds__(256) void gemm_bcast(const float* __restrict__ ctx,
                                                  const float* __restrict__ Wgen,
                                                  const float* __restrict__ bgen,
                                                  float* __restrict__ out) {
    __shared__ float part[4 * CG * PS];  // padded: [wave][c_local] stride PS
    const int tid   = threadIdx.x;
    const int w     = tid >> 6;
    const int lane  = tid & 63;
    const int cpart = lane >> 4;
    const int hp    = lane & 15;
    const int cblk  = blockIdx.x * CG;
    const int b0    = blockIdx.y * 4;

    const float4* W4 = reinterpret_cast<const float4*>(Wgen);
    const float4* X4 = reinterpret_cast<const float4*>(ctx);

    // ctx registers: xr[bb][j] = ctx[b0+bb][w*128 + j*64 + hp*4 .. +3]
    float4 xr[4][2];
    #pragma unroll
    for (int bb = 0; bb < 4; ++bb)
        #pragma unroll
        for (int j = 0; j < 2; ++j)
            xr[bb][j] = X4[(size_t)(b0 + bb) * 128 + w * 32 + j * 16 + hp];

    #pragma unroll
    for (int q = 0; q < CG / 4; ++q) {
        const int c = cblk + q * 4 + cpart;
        const size_t base = (size_t)c * 128 + w * 32 + hp;
        const float4 w0 = W4[base];
        const float4 w1 = W4[base + 16];
        const f2 w0lo = {w0.x, w0.y}, w0hi = {w0.z, w0.w};
        const f2 w1lo = {w1.x, w1.y}, w1hi = {w1.z, w1.w};
        float acc[4];
        #pragma unroll
        for (int bb = 0; bb < 4; ++bb) {
            f2 a2 = {0.f, 0.f};
            pkfma(a2, w0lo, (f2){xr[bb][0].x, xr[bb][0].y});
            pkfma(a2, w0hi, (f2){xr[bb][0].z, xr[bb][0].w});
            pkfma(a2, w1lo, (f2){xr[bb][1].x, xr[bb][1].y});
            pkfma(a2, w1hi, (f2){xr[bb][1].z, xr[bb][1].w});
            float a = a2.x + a2.y;
            a = ror_add<0x128>(a);
            a = ror_add<0x124>(a);
            a = ror_add<0x122>(a);
            a = ror_add<0x121>(a);      // full 16-lane sum in every lane
            acc[bb] = a;
        }
        if (hp == 0) {
            // 4 scalar writes at padded stride: lanes cpart 0..3 hit banks
            // {0,5,10,15}+base -> conflict-free
            float* p = part + (w * CG + q * 4 + cpart) * PS;
            #pragma unroll
            for (int bb = 0; bb < 4; ++bb) p[bb] = acc[bb];
        }
    }
    __syncthreads();

    // combine wave-partials + bias; padded reads map 32 (cq,bl) addrs onto all
    // 32 banks (j*5 rotation) -> conflict-free. Then float4 broadcast stores.
    {
        const int cq = tid & 7;
        const int bl = (tid >> 3) & 3;
        const int tt = tid >> 5;
        float v[4];
        #pragma unroll
        for (int j = 0; j < 4; ++j) {
            const int cl = cq * 4 + j;
            v[j] = part[(0 * CG + cl) * PS + bl] + part[(1 * CG + cl) * PS + bl]
                 + part[(2 * CG + cl) * PS + bl] + part[(3 * CG + cl) * PS + bl]
                 + bgen[cblk + cl];
        }
        const float4 vv = make_float4(v[0], v[1], v[2], v[3]);
        float* o = out + (size_t)(b0 + bl) * Td * Cd + cblk + cq * 4;
        #pragma unroll
        for (int k = 0; k < 4; ++k) {
            const int t = tt + k * 8;
            *reinterpret_cast<float4*>(o + (size_t)t * Cd) = vv;
        }
    }
}

extern "C" void kernel_launch(void* const* d_in, const int* in_sizes, int n_in,
                              void* d_out, int out_size, void* d_ws, size_t ws_size,
                              hipStream_t stream) {
    const float* fmap = (const float*)d_in[0];   // [64,512,8,32]
    const float* Wgen = (const float*)d_in[9];   // [4096,512]
    const float* bgen = (const float*)d_in[10];  // [4096]
    float* out = (float*)d_out;                  // [64,32,4096]
    float* ctx = (float*)d_ws;                   // [64,512] scratch

    reduce_rows<<<dim3((Bd * Hd) / (4 * 8)), dim3(256), 0, stream>>>(fmap, ctx);
    gemm_bcast<<<dim3(Cd / CG, Bd / 4), dim3(256), 0, stream>>>(ctx, Wgen, bgen, out);
}